// Round 10
// baseline (169.004 us; speedup 1.0000x reference)
//
#include <hip/hip_runtime.h>
#include <hip/hip_bf16.h>
#include <cstdint>

static constexpr int   Nb = 2;
static constexpr int   L  = 4800;
static constexpr int   S  = 4800;
static constexpr int   C  = 256;
static constexpr float THR = 0.2f;
static constexpr float SIM_SCALE = 1.0f / 25.6f;   // 1/(sqrt(C)*sqrt(C)*TEMP)
static constexpr unsigned CAND_CAP = 65536;        // hard math bound 38400 (<=4/row)

using f32x4  = __attribute__((ext_vector_type(4))) float;
using bf16x8 = __attribute__((ext_vector_type(8))) short;
using u32x4  = __attribute__((ext_vector_type(4))) unsigned int;

// ---------------- fp32 -> bf16 (RNE), both inputs; stats zeroing folded in ----------------
__device__ inline unsigned short bf16_rne(float x) {
    unsigned u = __float_as_uint(x);
    return (unsigned short)((u + 0x7FFFu + ((u >> 16) & 1u)) >> 16);
}

__global__ __launch_bounds__(256) void cvt_bf16(const float* __restrict__ in0,
                                                const float* __restrict__ in1,
                                                unsigned short* __restrict__ out0,
                                                unsigned short* __restrict__ out1,
                                                int n8,
                                                unsigned* __restrict__ stats, int nStats) {
    if (blockIdx.y == 0) {
        int si = blockIdx.x * 256 + threadIdx.x;
        if (si < nStats) stats[si] = 0u;
    }
    const float* in = blockIdx.y ? in1 : in0;
    unsigned short* out = blockIdx.y ? out1 : out0;
    int i = blockIdx.x * 256 + threadIdx.x;
    if (i >= n8) return;
    f32x4 a = *(const f32x4*)(in + (size_t)i * 8);
    f32x4 b = *(const f32x4*)(in + (size_t)i * 8 + 4);
    union { unsigned short us[8]; u32x4 v; } r;
#pragma unroll
    for (int j = 0; j < 4; j++) r.us[j] = bf16_rne(a[j]);
#pragma unroll
    for (int j = 0; j < 4; j++) r.us[4 + j] = bf16_rne(b[j]);
    *(u32x4*)(out + (size_t)i * 8) = r.v;
}

__device__ inline bool border_ok(int idx) {
    int h = idx / 80, w = idx % 80;
    return (h >= 2) & (h < 58) & (w >= 2) & (w < 78);
}

// ---------------- single GEMM pass: sums + e(fp16, coalesced) + mask zero ----------------
// Tile 96x192, 4 waves (2x2), wave-tile 48x96 = 3x6 frags mfma 16x16x32 bf16
// (swapped operands: lane&15 -> l, (lane>>4)*4+r -> s).
// Staging: global_load_lds dwordx4, pre-swizzled source, linear LDS dest,
// XOR-swizzled ds_read (rule-21). XCD-aware bijective block swizzle (T1/m204).
// Epilogue: exp-sums atomics; e -> LDS (XOR-swizzled 8B writes, ~2-way = free)
// -> 16B/lane fully-coalesced fp16 global store (fixes R4's 32B-segment
// scatter, the identified +30us regression); mask-zero linear chunk.
#define BM 96
#define BN 192
#define BK 64

static constexpr int NWG   = (L / BM) * (S / BN) * Nb;   // 2500
static constexpr int TILE_X = S / BN;                    // 25
static constexpr int TILES_PER_N = (L / BM) * TILE_X;    // 1250
static constexpr int XQ = NWG / 8;                       // 312
static constexpr int XR = NWG % 8;                       // 4

__device__ inline void gload16(const void* g, void* l) {
    __builtin_amdgcn_global_load_lds(
        (const __attribute__((address_space(1))) unsigned int*)g,
        (__attribute__((address_space(3))) unsigned int*)l, 16, 0, 0);
}

__global__ __launch_bounds__(256) void gemm_sums_e(
    const unsigned short* __restrict__ Abf,  // [N,L,C]
    const unsigned short* __restrict__ Bbf,  // [N,S,C]
    unsigned short* __restrict__ eh,         // [N,L,S] fp16 exp(sim)
    float* __restrict__ rowSum,              // [N,L]
    float* __restrict__ colSum,              // [N,S]
    float* __restrict__ mask)                // [N,L,S] zeroed here
{
    __shared__ __align__(16) unsigned short smem[BM * BK + BN * BK];  // 36 KB
    unsigned short* As = smem;
    unsigned short* Bs = smem + BM * BK;
    // epilogue aliases all 36 KB as the e tile: [96][192] fp16 = 36864 B exactly

    // bijective XCD swizzle (m204)
    const int orig = blockIdx.x;
    const int xcd  = orig & 7;
    const int idx  = orig >> 3;
    const int wgid = (xcd < XR ? xcd * (XQ + 1) : XR * (XQ + 1) + (xcd - XR) * XQ) + idx;
    const int n    = wgid / TILES_PER_N;
    const int rem  = wgid % TILES_PER_N;
    const int rb   = (rem / TILE_X) * BM;
    const int cb   = (rem % TILE_X) * BN;

    const int t  = threadIdx.x;
    const int lane = t & 63;
    const int wid  = t >> 6;
    const int wr = wid >> 1, wc = wid & 1;

    const unsigned short* Ag = Abf + ((size_t)n * L + rb) * C;
    const unsigned short* Bg = Bbf + ((size_t)n * S + cb) * C;

    f32x4 acc[3][6] = {};

    for (int kt = 0; kt < C; kt += BK) {
#pragma unroll
        for (int i = 0; i < 3; i++) {
            int ix = wid * 192 + i * 64 + lane;
            int row = ix >> 3;
            int src = ((ix & 7) ^ (row & 7)) * 8 + kt;
            gload16(Ag + (size_t)row * C + src, &As[(wid * 192 + i * 64) * 8]);
        }
#pragma unroll
        for (int i = 0; i < 6; i++) {
            int ix = wid * 384 + i * 64 + lane;
            int row = ix >> 3;
            int src = ((ix & 7) ^ (row & 7)) * 8 + kt;
            gload16(Bg + (size_t)row * C + src, &Bs[(wid * 384 + i * 64) * 8]);
        }
        __syncthreads();

#pragma unroll
        for (int kk = 0; kk < 2; kk++) {
            bf16x8 a[3], b[6];
            const int kElem = kk * 32 + (lane >> 4) * 8;
#pragma unroll
            for (int f = 0; f < 3; f++) {
                int ra = wr * 48 + f * 16 + (lane & 15);
                a[f] = *(const bf16x8*)&As[ra * 64 + (kElem ^ ((ra & 7) << 3))];
            }
#pragma unroll
            for (int f = 0; f < 6; f++) {
                int rbi = wc * 96 + f * 16 + (lane & 15);
                b[f] = *(const bf16x8*)&Bs[rbi * 64 + (kElem ^ ((rbi & 7) << 3))];
            }
#pragma unroll
            for (int fi = 0; fi < 3; fi++)
#pragma unroll
                for (int fj = 0; fj < 6; fj++)
                    acc[fi][fj] = __builtin_amdgcn_mfma_f32_16x16x32_bf16(
                        b[fj], a[fi], acc[fi][fj], 0, 0, 0);
        }
        __syncthreads();
    }

    // ---- epilogue ----
    float csum[6][4] = {};
#pragma unroll
    for (int fi = 0; fi < 3; fi++) {
        const int bl = wr * 48 + fi * 16 + (lane & 15);      // block-local row 0..95
        float rsum = 0.f;
#pragma unroll
        for (int fj = 0; fj < 6; fj++) {
            const int bs = wc * 96 + fj * 16 + ((lane >> 4) << 2);  // block-local col
            union { _Float16 h[4]; unsigned long long u; } pk;
#pragma unroll
            for (int r = 0; r < 4; r++) {
                float e = __expf(acc[fi][fj][r] * SIM_SCALE);
                rsum += e;
                csum[fj][r] += e;
                pk.h[r] = (_Float16)e;
            }
            // e -> LDS, XOR-swizzled (write bs2^X, X=(bl&7)<<4; bit3 preserved)
            unsigned off = bl * 384 + ((bs * 2) ^ ((bl & 7) << 4));
            *(unsigned long long*)((char*)smem + off) = pk.u;
        }
        rsum += __shfl_xor(rsum, 16);
        rsum += __shfl_xor(rsum, 32);
        if (lane < 16)
            atomicAdd(&rowSum[(size_t)n * L + rb + bl], rsum);
    }
#pragma unroll
    for (int fj = 0; fj < 6; fj++)
#pragma unroll
        for (int r = 0; r < 4; r++) {
            float v = csum[fj][r];
            v += __shfl_xor(v, 1);
            v += __shfl_xor(v, 2);
            v += __shfl_xor(v, 4);
            v += __shfl_xor(v, 8);
            if ((lane & 15) == 0)
                atomicAdd(&colSum[(size_t)n * S + cb + wc * 96 + fj * 16 + ((lane >> 4) << 2) + r], v);
        }
    __syncthreads();                                     // e tile complete in LDS

    // coalesced e store: 2304 x 16B chunks (9/thread); chunk k of row = cols [8k,8k+8)
    const size_t ebase = ((size_t)n * L + rb) * S + cb;  // halfs
#pragma unroll
    for (int i = 0; i < 9; i++) {
        int chunk = i * 256 + t;                         // 0..2303
        int row = chunk / 24;                            // 24 x 16B per 384B row
        int k   = chunk % 24;
        unsigned lb = row * 384 + ((k * 16) ^ ((row & 7) << 4));
        u32x4 v = *(const u32x4*)((const char*)smem + lb);
        *(u32x4*)&eh[ebase + (size_t)row * S + k * 8] = v;
    }

    // mask-zero this tile's linear chunk (46.08M / 2500 = 18432 f32)
    const f32x4 zero4 = {0.f, 0.f, 0.f, 0.f};
    const size_t mbase = (size_t)wgid * 18432;
#pragma unroll
    for (int i = 0; i < 18; i++)
        *(f32x4*)&mask[mbase + ((size_t)i * 256 + t) * 4] = zero4;
}

// ---------------- streaming conf = e^2/(D1*D2) + maxes + candidates ----------------
__global__ __launch_bounds__(256) void stream_conf(
    const unsigned short* __restrict__ eh,   // [N,L,S] fp16
    const float* __restrict__ rowSum,        // [N,L]
    const float* __restrict__ colSum,        // [N,S]
    float* __restrict__ conf,                // [N,L,S]
    unsigned* __restrict__ rowMax,           // [N,L] bits
    unsigned* __restrict__ colMax,           // [N,S] bits
    unsigned* __restrict__ cnt,
    unsigned* __restrict__ cand)             // [CAP][2] flat,bits
{
    const int ROWS = 32;
    const int CBLK = 19;                     // ceil(4800/256)
    const int tilesPerN = (L / ROWS) * CBLK;
    const int wid = threadIdx.x >> 6, lane = threadIdx.x & 63;
    const int tw = blockIdx.x * 4 + wid;
    if (tw >= Nb * tilesPerN) return;
    const int n   = tw / tilesPerN;
    const int rem = tw % tilesPerN;
    const int r0  = (rem / CBLK) * ROWS;
    const int c   = (rem % CBLK) * 256 + lane * 4;
    const bool act = (c < S);

    f32x4 invD1 = {0.f, 0.f, 0.f, 0.f};
    bool bs4[4] = {false, false, false, false};
    if (act) {
        f32x4 d1 = *(const f32x4*)&colSum[(size_t)n * S + c];
#pragma unroll
        for (int j = 0; j < 4; j++) { invD1[j] = 1.0f / d1[j]; bs4[j] = border_ok(c + j); }
    }
    f32x4 cmax = {0.f, 0.f, 0.f, 0.f};

    for (int r = r0; r < r0 + ROWS; r++) {
        const float invD2 = 1.0f / rowSum[(size_t)n * L + r];
        const bool bl = border_ok(r);
        float rmax = 0.f;
        if (act) {
            union { unsigned long long u; _Float16 h[4]; } ev;
            ev.u = *(const unsigned long long*)&eh[((size_t)n * L + r) * S + c];
            f32x4 cv;
#pragma unroll
            for (int j = 0; j < 4; j++) {
                float e = (float)ev.h[j];
                float cf = e * e * invD1[j] * invD2;
                cv[j] = cf;
                rmax = fmaxf(rmax, cf);
                cmax[j] = fmaxf(cmax[j], cf);
                if (cf > THR && bl && bs4[j]) {
                    unsigned pos = atomicAdd(cnt, 1u);
                    if (pos < CAND_CAP) {
                        cand[2 * pos]     = (unsigned)(((size_t)n * L + r) * S + c + j);
                        cand[2 * pos + 1] = __float_as_uint(cf);
                    }
                }
            }
            *(f32x4*)&conf[((size_t)n * L + r) * S + c] = cv;
        }
#pragma unroll
        for (int d = 1; d < 64; d <<= 1) rmax = fmaxf(rmax, __shfl_xor(rmax, d));
        if (lane == 0)
            atomicMax(&rowMax[(size_t)n * L + r], __float_as_uint(rmax));
    }
    if (act) {
#pragma unroll
        for (int j = 0; j < 4; j++)
            atomicMax(&colMax[(size_t)n * S + c + j], __float_as_uint(cmax[j]));
    }
}

// ---------------- scatter the mutual-NN survivors ----------------
__global__ __launch_bounds__(256) void mask_scatter(
    const unsigned* __restrict__ cnt,
    const unsigned* __restrict__ cand,
    const unsigned* __restrict__ rowMax,
    const unsigned* __restrict__ colMax,
    float* __restrict__ mask)
{
    unsigned nc = *cnt;
    if (nc > CAND_CAP) nc = CAND_CAP;
    for (unsigned i = blockIdx.x * 256 + threadIdx.x; i < nc; i += gridDim.x * 256) {
        unsigned flat = cand[2 * i];
        unsigned bits = cand[2 * i + 1];
        unsigned row = flat / S;          // n*L + l
        unsigned s   = flat % S;
        unsigned n   = row / L;
        if (bits == rowMax[row] && bits == colMax[n * S + s])
            mask[flat] = 1.0f;
    }
}

// ---------------- launch ----------------
extern "C" void kernel_launch(void* const* d_in, const int* in_sizes, int n_in,
                              void* d_out, int out_size, void* d_ws, size_t ws_size,
                              hipStream_t stream) {
    (void)in_sizes; (void)n_in; (void)out_size; (void)ws_size;
    const float* f0 = (const float*)d_in[0];
    const float* f1 = (const float*)d_in[1];

    float* conf = (float*)d_out;                          // N*L*S f32
    float* mask = conf + (size_t)Nb * L * S;

    unsigned short* Abf = (unsigned short*)d_ws;          // 4.92 MB
    unsigned short* Bbf = Abf + (size_t)Nb * L * C;       // 4.92 MB
    float* rowSum = (float*)(Bbf + (size_t)Nb * S * C);   // 9600 f32
    float* colSum = rowSum + (size_t)Nb * L;
    unsigned* rowMax = (unsigned*)(colSum + (size_t)Nb * S);
    unsigned* colMax = rowMax + (size_t)Nb * L;
    unsigned* cnt    = colMax + (size_t)Nb * S;           // +3 pad for alignment
    unsigned* cand   = cnt + 4;                           // 512 KB
    unsigned short* eh = (unsigned short*)(cand + 2 * CAND_CAP); // 92.16 MB fp16

    const int nStats = 2 * (Nb * L + Nb * S) + 4;         // sums + maxes + counter(+pad)
    const int n8 = Nb * L * C / 8;
    cvt_bf16<<<dim3((n8 + 255) / 256, 2), 256, 0, stream>>>(f0, f1, Abf, Bbf, n8,
                                                            (unsigned*)rowSum, nStats);

    gemm_sums_e<<<NWG, 256, 0, stream>>>(Abf, Bbf, eh, rowSum, colSum, mask);

    const int nTiles = Nb * (L / 32) * 19;
    stream_conf<<<(nTiles + 3) / 4, 256, 0, stream>>>(eh, rowSum, colSum, conf,
                                                      rowMax, colMax, cnt, cand);

    mask_scatter<<<32, 256, 0, stream>>>(cnt, cand, rowMax, colMax, mask);
}